// Round 1
// baseline (447.781 us; speedup 1.0000x reference)
//
#include <hip/hip_runtime.h>
#include <hip/hip_bf16.h>

typedef unsigned short u16;
typedef __bf16 bf16x8 __attribute__((ext_vector_type(8)));
typedef float f32x4 __attribute__((ext_vector_type(4)));

#define BM 128
#define BN 128
#define BK 32

// ---------------------------------------------------------------------------
// Prep 1: x fp32 -> bf16 (RN), plus fp32 row sums. One block per row.
// ---------------------------------------------------------------------------
__device__ __forceinline__ u16 f2b(float f) {
    union { __hip_bfloat16 h; u16 u; } cv;
    cv.h = __float2bfloat16(f);
    return cv.u;
}

__global__ __launch_bounds__(256) void prep_x(const float* __restrict__ x,
                                              u16* __restrict__ xb,
                                              float* __restrict__ rowsum,
                                              int K) {
    const int row = blockIdx.x;
    const float* xr = x + (size_t)row * K;
    u16* xbr = xb + (size_t)row * K;
    float s = 0.f;
    for (int c = threadIdx.x * 4; c < K; c += blockDim.x * 4) {
        float4 v = *reinterpret_cast<const float4*>(xr + c);
        s += v.x + v.y + v.z + v.w;
        ushort4 o;
        o.x = f2b(v.x); o.y = f2b(v.y); o.z = f2b(v.z); o.w = f2b(v.w);
        *reinterpret_cast<ushort4*>(xbr + c) = o;
    }
    // wave reduce (64 lanes), then cross-wave via LDS
    #pragma unroll
    for (int off = 32; off > 0; off >>= 1) s += __shfl_down(s, off);
    __shared__ float wsum[4];
    const int lane = threadIdx.x & 63, wv = threadIdx.x >> 6;
    if (lane == 0) wsum[wv] = s;
    __syncthreads();
    if (threadIdx.x == 0) rowsum[row] = wsum[0] + wsum[1] + wsum[2] + wsum[3];
}

// ---------------------------------------------------------------------------
// Prep 2: weight int32 codes (exact in bf16) -> bf16. Truncation is exact
// for |v| <= 128, so just take the top 16 bits of the float.
// ---------------------------------------------------------------------------
__global__ __launch_bounds__(256) void prep_w(const int* __restrict__ w,
                                              u16* __restrict__ wb) {
    const size_t idx = (size_t)blockIdx.x * blockDim.x + threadIdx.x;
    const size_t e = idx * 4;
    int4 v = *reinterpret_cast<const int4*>(w + e);
    ushort4 o;
    o.x = (u16)(__float_as_uint((float)v.x) >> 16);
    o.y = (u16)(__float_as_uint((float)v.y) >> 16);
    o.z = (u16)(__float_as_uint((float)v.z) >> 16);
    o.w = (u16)(__float_as_uint((float)v.w) >> 16);
    *reinterpret_cast<ushort4*>(wb + e) = o;
}

// ---------------------------------------------------------------------------
// GEMM: C[m,o] = scale[o]*(sum_k A[m,k]*B[o,k] - zp[o]*rowsum[m]) + bias[o]
// A: M x K bf16 row-major; B: N x K bf16 row-major (i.e. B^T GEMM).
// m97 structure: 128x128 tile, BK=32, 4 waves (2x2), global_load_lds w=16.
// ---------------------------------------------------------------------------
__device__ __forceinline__ void async16(void* lds, const void* g) {
    __builtin_amdgcn_global_load_lds(
        (const __attribute__((address_space(1))) unsigned*)g,
        (__attribute__((address_space(3))) unsigned*)lds, 16, 0, 0);
}

__global__ __launch_bounds__(256) void qgemm(
    const u16* __restrict__ A, const u16* __restrict__ B,
    const float* __restrict__ rowsum, const float* __restrict__ scale,
    const float* __restrict__ zp, const float* __restrict__ bias,
    float* __restrict__ C, int M, int N, int K) {
    __shared__ __align__(16) u16 As[BM * BK];
    __shared__ __align__(16) u16 Bs[BN * BK];

    const int tid  = threadIdx.x;
    const int lane = tid & 63;
    const int wave = tid >> 6;
    const int wm = wave >> 1;   // 0..1
    const int wn = wave & 1;    // 0..1
    const int bn = blockIdx.x, bm = blockIdx.y;

    const size_t a_off = (size_t)bm * BM * K;
    const size_t b_off = (size_t)bn * BN * K;

    f32x4 acc[4][4] = {};

    const int lr = lane & 15;          // fragment row (A) / col (B,D)
    const int lk = (lane >> 4) << 3;   // fragment k offset: 0,8,16,24

    for (int kt = 0; kt < K; kt += BK) {
        // stage A and B tiles: 8192 B each, 512 x 16B issues -> 2 per thread
        #pragma unroll
        for (int j = 0; j < 2; ++j) {
            const int li = tid + j * 256;       // 0..511
            const int r  = li >> 2;             // tile row 0..127
            const int ko = (li & 3) << 3;       // k elem offset 0,8,16,24
            async16((char*)As + li * 16, A + a_off + (size_t)r * K + kt + ko);
            async16((char*)Bs + li * 16, B + b_off + (size_t)r * K + kt + ko);
        }
        __syncthreads();   // compiler emits vmcnt(0) drain before barrier

        bf16x8 af[4], bfr[4];
        #pragma unroll
        for (int m = 0; m < 4; ++m) {
            af[m]  = *reinterpret_cast<const bf16x8*>(&As[(wm * 64 + m * 16 + lr) * BK + lk]);
            bfr[m] = *reinterpret_cast<const bf16x8*>(&Bs[(wn * 64 + m * 16 + lr) * BK + lk]);
        }
        #pragma unroll
        for (int m = 0; m < 4; ++m)
            #pragma unroll
            for (int n = 0; n < 4; ++n)
                acc[m][n] = __builtin_amdgcn_mfma_f32_16x16x32_bf16(
                    af[m], bfr[n], acc[m][n], 0, 0, 0);
        __syncthreads();   // protect LDS from next-tile overwrite
    }

    // Epilogue: fused dequant. D layout: col = lane&15, row = 4*(lane>>4)+i.
    float sc[4], zz[4], bb[4];
    #pragma unroll
    for (int n = 0; n < 4; ++n) {
        const int o = bn * BN + wn * 64 + n * 16 + lr;
        sc[n] = scale[o]; zz[n] = zp[o]; bb[n] = bias[o];
    }
    #pragma unroll
    for (int m = 0; m < 4; ++m) {
        const int r0 = bm * BM + wm * 64 + m * 16 + ((lane >> 4) << 2);
        float rs[4];
        #pragma unroll
        for (int i = 0; i < 4; ++i) rs[i] = rowsum[r0 + i];
        #pragma unroll
        for (int n = 0; n < 4; ++n) {
            const int o = bn * BN + wn * 64 + n * 16 + lr;
            #pragma unroll
            for (int i = 0; i < 4; ++i)
                C[(size_t)(r0 + i) * N + o] =
                    sc[n] * (acc[m][n][i] - zz[n] * rs[i]) + bb[n];
        }
    }
}

// ---------------------------------------------------------------------------
extern "C" void kernel_launch(void* const* d_in, const int* in_sizes, int n_in,
                              void* d_out, int out_size, void* d_ws, size_t ws_size,
                              hipStream_t stream) {
    const float* x     = (const float*)d_in[0];
    const int*   w     = (const int*)d_in[1];
    const float* scale = (const float*)d_in[2];
    const float* zp    = (const float*)d_in[3];
    const float* bias  = (const float*)d_in[4];
    float* out = (float*)d_out;

    const int N = in_sizes[2];              // D_OUT = 4096
    const int K = in_sizes[1] / N;          // D_IN  = 4096
    const int M = in_sizes[0] / K;          // B*S   = 8192

    u16*   xb = (u16*)d_ws;
    u16*   wb = (u16*)((char*)d_ws + (size_t)M * K * 2);
    float* rs = (float*)((char*)d_ws + (size_t)M * K * 2 + (size_t)N * K * 2);

    prep_x<<<M, 256, 0, stream>>>(x, xb, rs, K);
    prep_w<<<(int)(((size_t)N * K / 4) / 256), 256, 0, stream>>>(w, wb);

    dim3 grid(N / BN, M / BM);
    qgemm<<<grid, 256, 0, stream>>>(xb, wb, rs, scale, zp, bias, out, M, N, K);
}

// Round 2
// 279.414 us; speedup vs baseline: 1.6026x; 1.6026x over previous
//
#include <hip/hip_runtime.h>
#include <hip/hip_bf16.h>

typedef unsigned short u16;
typedef __bf16 bf16x8 __attribute__((ext_vector_type(8)));
typedef float f32x4 __attribute__((ext_vector_type(4)));

// ---------------------------------------------------------------------------
// Prep 1: x fp32 -> bf16 (RN), plus fp32 row sums. One block per row.
// ---------------------------------------------------------------------------
__device__ __forceinline__ u16 f2b(float f) {
    union { __hip_bfloat16 h; u16 u; } cv;
    cv.h = __float2bfloat16(f);
    return cv.u;
}

__global__ __launch_bounds__(256) void prep_x(const float* __restrict__ x,
                                              u16* __restrict__ xb,
                                              float* __restrict__ rowsum,
                                              int K) {
    const int row = blockIdx.x;
    const float* xr = x + (size_t)row * K;
    u16* xbr = xb + (size_t)row * K;
    float s = 0.f;
    for (int c = threadIdx.x * 4; c < K; c += blockDim.x * 4) {
        float4 v = *reinterpret_cast<const float4*>(xr + c);
        s += v.x + v.y + v.z + v.w;
        ushort4 o;
        o.x = f2b(v.x); o.y = f2b(v.y); o.z = f2b(v.z); o.w = f2b(v.w);
        *reinterpret_cast<ushort4*>(xbr + c) = o;
    }
    #pragma unroll
    for (int off = 32; off > 0; off >>= 1) s += __shfl_down(s, off);
    __shared__ float wsum[4];
    const int lane = threadIdx.x & 63, wv = threadIdx.x >> 6;
    if (lane == 0) wsum[wv] = s;
    __syncthreads();
    if (threadIdx.x == 0) rowsum[row] = wsum[0] + wsum[1] + wsum[2] + wsum[3];
}

// ---------------------------------------------------------------------------
// Prep 2: weight int32 codes (exact in bf16) -> bf16.
// ---------------------------------------------------------------------------
__global__ __launch_bounds__(256) void prep_w(const int* __restrict__ w,
                                              u16* __restrict__ wb) {
    const size_t idx = (size_t)blockIdx.x * blockDim.x + threadIdx.x;
    const size_t e = idx * 4;
    int4 v = *reinterpret_cast<const int4*>(w + e);
    ushort4 o;
    o.x = (u16)(__float_as_uint((float)v.x) >> 16);
    o.y = (u16)(__float_as_uint((float)v.y) >> 16);
    o.z = (u16)(__float_as_uint((float)v.z) >> 16);
    o.w = (u16)(__float_as_uint((float)v.w) >> 16);
    *reinterpret_cast<ushort4*>(wb + e) = o;
}

// ---------------------------------------------------------------------------
// 8-phase 256x256 GEMM (m201 template), fused dequant epilogue.
// C[m,o] = scale[o]*(sum_k A[m,k]*B[o,k] - zp[o]*rowsum[m]) + bias[o]
// A: M x K bf16 row-major; B: N x K bf16 row-major (B^T GEMM).
// LDS: A halves [buf][ks][256 rows][32 k] (16 KiB each) at 0; B at +64 KiB.
// Swizzle: 16B slot within a row's 64B: slot_phys = slot_log ^ ((row>>1)&3).
// Staged linearly via global_load_lds from inverse-swizzled global source.
// ---------------------------------------------------------------------------
__device__ __forceinline__ void async16(void* lds, const void* g) {
    __builtin_amdgcn_global_load_lds(
        (const __attribute__((address_space(1))) unsigned*)g,
        (__attribute__((address_space(3))) unsigned*)lds, 16, 0, 0);
}

__global__ __launch_bounds__(512, 2) void qgemm8(
    const u16* __restrict__ A, const u16* __restrict__ B,
    const float* __restrict__ rowsum, const float* __restrict__ scale,
    const float* __restrict__ zp, const float* __restrict__ bias,
    float* __restrict__ C, int M, int N, int K) {
    extern __shared__ char smem[];
    char* const AsB = smem;            // 4 x 16 KiB A half-tiles
    char* const BsB = smem + 65536;    // 4 x 16 KiB B half-tiles

    const int tid  = threadIdx.x;
    const int lane = tid & 63;
    const int wid  = tid >> 6;
    const int wm = wid >> 2, wn = wid & 3;   // 2 x 4 waves
    const int l15 = lane & 15;

    // bijective XCD swizzle (gridDim.x % 8 == 0)
    const int nbn = N >> 8;
    int wg = blockIdx.x;
    wg = (wg & 7) * (gridDim.x >> 3) + (wg >> 3);
    const int bm = wg / nbn, bn = wg % nbn;

    // per-thread staging source offsets (inverse-swizzled global address)
    const int r0s = tid >> 2, sls = tid & 3;
    size_t a_src[2], b_src[2];
    int lds_off[2];
    #pragma unroll
    for (int j = 0; j < 2; ++j) {
        const int row = r0s + j * 128;
        const int sl  = sls ^ ((row >> 1) & 3);
        a_src[j] = ((size_t)(bm * 256 + row)) * K + sl * 8;
        b_src[j] = ((size_t)(bn * 256 + row)) * K + sl * 8;
        lds_off[j] = (j * 512 + tid) * 16;
    }

    auto stageA = [&](int u, int ks, int buf) {
        const int kc = u * 64 + ks * 32;
        char* const dst = AsB + (buf * 2 + ks) * 16384;
        #pragma unroll
        for (int j = 0; j < 2; ++j) async16(dst + lds_off[j], A + a_src[j] + kc);
    };
    auto stageB = [&](int u, int ks, int buf) {
        const int kc = u * 64 + ks * 32;
        char* const dst = BsB + (buf * 2 + ks) * 16384;
        #pragma unroll
        for (int j = 0; j < 2; ++j) async16(dst + lds_off[j], B + b_src[j] + kc);
    };

    // fragment-read constants (swizzled ds_read address)
    const int sw16 = (((lane >> 4) ^ ((lane >> 1) & 3)) << 4);
    const int a_ro = (wm * 128 + l15) * 64 + sw16;   // + mf*1024
    const int b_ro = (wn * 64 + l15) * 64 + sw16;    // + nf*1024

    f32x4 acc[8][4] = {};
    bf16x8 bf[4];

    const int NT  = K >> 6;    // K/64 tiles
    const int NIT = NT >> 1;   // 2 tiles / iteration

    // ---- prologue: tile0 {B0,A0,B1,A1}; tile1 {B0,A0,B1} stays in flight ----
    stageB(0, 0, 0); stageA(0, 0, 0); stageB(0, 1, 0); stageA(0, 1, 0);
    asm volatile("s_waitcnt vmcnt(4)" ::: "memory");
    stageB(1, 0, 1); stageA(1, 0, 1); stageB(1, 1, 1);
    asm volatile("s_waitcnt vmcnt(6)" ::: "memory");
    asm volatile("s_barrier" ::: "memory");

#define PHASE(BUF, KS, QM, LOADB, STAGE, WAITV)                                \
    {                                                                          \
        const char* ha = AsB + ((BUF) * 2 + (KS)) * 16384;                     \
        const char* hb = BsB + ((BUF) * 2 + (KS)) * 16384;                     \
        bf16x8 af[4];                                                          \
        _Pragma("unroll")                                                      \
        for (int m = 0; m < 4; ++m)                                            \
            af[m] = *(const bf16x8*)(ha + a_ro + ((QM) * 4 + m) * 1024);       \
        if (LOADB) {                                                           \
            _Pragma("unroll")                                                  \
            for (int n = 0; n < 4; ++n)                                        \
                bf[n] = *(const bf16x8*)(hb + b_ro + n * 1024);                \
        }                                                                      \
        STAGE;                                                                 \
        asm volatile("s_barrier" ::: "memory");                                \
        asm volatile("s_waitcnt lgkmcnt(0)" ::: "memory");                     \
        __builtin_amdgcn_sched_barrier(0);                                     \
        __builtin_amdgcn_s_setprio(1);                                         \
        _Pragma("unroll")                                                      \
        for (int m = 0; m < 4; ++m) {                                          \
            _Pragma("unroll")                                                  \
            for (int n = 0; n < 4; ++n)                                        \
                acc[(QM) * 4 + m][n] =                                         \
                    __builtin_amdgcn_mfma_f32_16x16x32_bf16(                   \
                        af[m], bf[n], acc[(QM) * 4 + m][n], 0, 0, 0);          \
        }                                                                      \
        __builtin_amdgcn_s_setprio(0);                                         \
        __builtin_amdgcn_sched_barrier(0);                                     \
        if (WAITV) asm volatile("s_waitcnt vmcnt(6)" ::: "memory");            \
        asm volatile("s_barrier" ::: "memory");                                \
    }

    #pragma unroll 1
    for (int i = 0; i < NIT; ++i) {
        const int t  = 2 * i;
        const int u1 = t + 1;
        int u2 = t + 2; if (u2 >= NT) u2 = NT - 1;   // clamped dummy prefetch
        int u3 = t + 3; if (u3 >= NT) u3 = NT - 1;   // (keeps vmcnt bookkeeping)
        PHASE(0, 0, 0, 1, stageA(u1, 1, 1), 0)   // reads t:A0,B0   | stage (t+1)A1
        PHASE(0, 0, 1, 0, stageB(u2, 0, 0), 0)   // reads t:A0     | stage (t+2)B0
        PHASE(0, 1, 0, 1, stageA(u2, 0, 0), 0)   // reads t:A1,B1  | stage (t+2)A0
        PHASE(0, 1, 1, 0, stageB(u2, 1, 0), 1)   // reads t:A1     | stage (t+2)B1 + vmcnt(6)
        PHASE(1, 0, 0, 1, stageA(u2, 1, 0), 0)   // reads t+1:A0,B0| stage (t+2)A1
        PHASE(1, 0, 1, 0, stageB(u3, 0, 1), 0)   // reads t+1:A0   | stage (t+3)B0
        PHASE(1, 1, 0, 1, stageA(u3, 0, 1), 0)   // reads t+1:A1,B1| stage (t+3)A0
        PHASE(1, 1, 1, 0, stageB(u3, 1, 1), 1)   // reads t+1:A1   | stage (t+3)B1 + vmcnt(6)
    }
#undef PHASE

    // ---- epilogue: fused dequant. D: col=lane&15, row=4*(lane>>4)+i ----
    float sc[4], zz[4], bb[4];
    #pragma unroll
    for (int n = 0; n < 4; ++n) {
        const int o = bn * 256 + wn * 64 + n * 16 + l15;
        sc[n] = scale[o]; zz[n] = zp[o]; bb[n] = bias[o];
    }
    const int hi4 = (lane >> 4) << 2;
    #pragma unroll
    for (int mf = 0; mf < 8; ++mf) {
        const int r0 = bm * 256 + wm * 128 + mf * 16 + hi4;
        float rs[4];
        #pragma unroll
        for (int i = 0; i < 4; ++i) rs[i] = rowsum[r0 + i];
        #pragma unroll
        for (int n = 0; n < 4; ++n) {
            const int o = bn * 256 + wn * 64 + n * 16 + l15;
            #pragma unroll
            for (int i = 0; i < 4; ++i)
                C[(size_t)(r0 + i) * N + o] =
                    sc[n] * (acc[mf][n][i] - zz[n] * rs[i]) + bb[n];
        }
    }
}

// ---------------------------------------------------------------------------
extern "C" void kernel_launch(void* const* d_in, const int* in_sizes, int n_in,
                              void* d_out, int out_size, void* d_ws, size_t ws_size,
                              hipStream_t stream) {
    const float* x     = (const float*)d_in[0];
    const int*   w     = (const int*)d_in[1];
    const float* scale = (const float*)d_in[2];
    const float* zp    = (const float*)d_in[3];
    const float* bias  = (const float*)d_in[4];
    float* out = (float*)d_out;

    const int N = in_sizes[2];              // D_OUT = 4096
    const int K = in_sizes[1] / N;          // D_IN  = 4096
    const int M = in_sizes[0] / K;          // B*S   = 8192

    u16*   xb = (u16*)d_ws;
    u16*   wb = (u16*)((char*)d_ws + (size_t)M * K * 2);
    float* rs = (float*)((char*)d_ws + (size_t)M * K * 2 + (size_t)N * K * 2);

    prep_x<<<M, 256, 0, stream>>>(x, xb, rs, K);
    prep_w<<<(int)(((size_t)N * K / 4) / 256), 256, 0, stream>>>(w, wb);

    (void)hipFuncSetAttribute((const void*)qgemm8,
                              hipFuncAttributeMaxDynamicSharedMemorySize, 131072);
    const int nwg = (M / 256) * (N / 256);   // 512, % 8 == 0
    qgemm8<<<nwg, 512, 131072, stream>>>(xb, wb, rs, scale, zp, bias, out, M, N, K);
}